// Round 8
// baseline (80.929 us; speedup 1.0000x reference)
//
#include <hip/hip_runtime.h>

// z[b,c,m] = sum_d S[m,c,d] * (x[b,d,m] - mean[d,m])
// B=1024, C=64, M=512. x:(B,C,M) f32, mean:(1,C,M), S:(M,C,C), out f32.
//
// v7: 512-thr blocks (8 waves, 1 m/wave, MT=8), BT=16, NB=8 -> grid 512
// = 2 blocks/CU (VGPR<=128, LDS 64 KB). Single x LDS buffer + reg-held
// prefetch (depth 2); 2 lgkmcnt-only barriers/iter (vmcnt never drained).

typedef __attribute__((ext_vector_type(8))) short short8;
typedef __attribute__((ext_vector_type(4))) float f32x4;

namespace {
constexpr int Mm = 512, Cc = 64, Bb = 1024;
constexpr int MT = 8;   // m per block (1 per wave)
constexpr int BT = 16;  // b per iteration
constexpr int NB = 8;   // iterations (b-range 128)
constexpr int ZP = 12;  // z row pitch (8 m + 4 pad), 48B rows
constexpr size_t LDSB = 128 * 128 + 1024 * ZP * 4;  // 16 KB x + 48 KB z = 64 KB

__device__ __forceinline__ unsigned short f2bf(float v) {  // RNE f32->bf16
  unsigned uu = __float_as_uint(v);
  uu = (uu + 0x7fffu + ((uu >> 16) & 1u)) >> 16;
  return (unsigned short)uu;
}
__device__ __forceinline__ unsigned pack2(float a, float b) {
  return (unsigned)f2bf(a) | ((unsigned)f2bf(b) << 16);
}
}  // namespace

#define ELEM(V, I) \
  ((I) == 0 ? (V).x : (I) == 1 ? (V).y : (I) == 2 ? (V).z : (V).w)

__global__ __launch_bounds__(512, 4) void zca_v7(
    const float* __restrict__ x, const float* __restrict__ mean,
    const float* __restrict__ S, float* __restrict__ out) {
  extern __shared__ unsigned char lds[];
  unsigned char* xl = lds;            // bf16 x tile [row=m*16+b][d], 128B rows
  float* zl = (float*)(lds + 16384);  // z transpose, 1024 rows x ZP floats

  const int tid = threadIdx.x;
  const int l = tid & 63;
  const int w = __builtin_amdgcn_readfirstlane(tid >> 6);  // wave = m_local

  // bijective XCD swizzle: 512 blocks; per XCD: 8 m-tiles x 8 b-groups
  const int id = blockIdx.x;
  const int sw = ((id & 7) << 6) + (id >> 3);
  const int m0 = (sw >> 3) * MT;
  const int b0 = (sw & 7) * (BT * NB);

  const int mq = l & 1;   // m-half (float4 of 4 m)
  const int e = l >> 1;   // 0..31 -> d-pair index
  const int g2 = w >> 1;  // uniform: z-read un-permute key

#define ISSUE(ST, T)                                                         \
  {                                                                          \
    _Pragma("unroll") for (int dd = 0; dd < 2; ++dd)                         \
        _Pragma("unroll") for (int p = 0; p < 2; ++p)                        \
            ST[dd * 2 + p] = *(const float4*)(                               \
                x + (size_t)((b0 + (T)*BT + p * 8 + w) * Cc + 2 * e + dd) *  \
                        Mm + m0 + mq * 4);                                   \
  }

  // x-LDS: row=(m*16+b), chunk cf=d>>3 stored at cf^(row&7) (row&7==w here)
#define STAGE(ST)                                                            \
  {                                                                          \
    _Pragma("unroll") for (int p = 0; p < 2; ++p) {                          \
      _Pragma("unroll") for (int i = 0; i < 4; ++i) {                        \
        const int row = (mq * 4 + i) * BT + p * 8 + w;                       \
        const unsigned v = pack2(ELEM(ST[p], i) - ELEM(mvE, i),              \
                                 ELEM(ST[2 + p], i) - ELEM(mvO, i));         \
        *(unsigned*)(xl + row * 128 + (((e >> 2) ^ w) << 4) +                \
                     ((e & 3) << 2)) = v;                                    \
      }                                                                      \
    }                                                                        \
  }

#define BAR()                                          \
  {                                                    \
    asm volatile("s_waitcnt lgkmcnt(0)" ::: "memory"); \
    __builtin_amdgcn_s_barrier();                      \
  }

  float4 st0[4], st1[4];

  // ---- prologue ----
  ISSUE(st0, 0)
  ISSUE(st1, 1)
  const float4 mvE =
      *(const float4*)(mean + (size_t)(2 * e) * Mm + m0 + mq * 4);
  const float4 mvO =
      *(const float4*)(mean + (size_t)(2 * e + 1) * Mm + m0 + mq * 4);

  short8 A[4][2];
#pragma unroll
  for (int ct = 0; ct < 4; ++ct) {
#pragma unroll
    for (int ks = 0; ks < 2; ++ks) {
      const float* sp = S + ((size_t)(m0 + w) * Cc + ct * 16 + (l & 15)) * Cc +
                        ks * 32 + (l >> 4) * 8;
      const float4 f0 = *(const float4*)sp;
      const float4 f1 = *(const float4*)(sp + 4);
      short8 a;
      a[0] = (short)f2bf(f0.x); a[1] = (short)f2bf(f0.y);
      a[2] = (short)f2bf(f0.z); a[3] = (short)f2bf(f0.w);
      a[4] = (short)f2bf(f1.x); a[5] = (short)f2bf(f1.y);
      a[6] = (short)f2bf(f1.z); a[7] = (short)f2bf(f1.w);
      A[ct][ks] = a;
    }
  }
  STAGE(st0)
  BAR()

#define ITER(T, STC, STN)                                                      \
  {                                                                            \
    const int rb = (w * 16 + (l & 15)) * 128;                                  \
    const short8 Bf0 =                                                         \
        *(const short8*)(xl + rb + ((((l >> 4)) ^ (l & 7)) << 4));             \
    const short8 Bf1 =                                                         \
        *(const short8*)(xl + rb + (((4 | (l >> 4)) ^ (l & 7)) << 4));         \
    if ((T) + 2 < NB) ISSUE(STN, (T) + 2)                                      \
    f32x4 acc[4];                                                              \
    _Pragma("unroll") for (int ct = 0; ct < 4; ++ct) acc[ct] =                 \
        (f32x4){0.f, 0.f, 0.f, 0.f};                                          \
    _Pragma("unroll") for (int ct = 0; ct < 4; ++ct) acc[ct] =                 \
        __builtin_amdgcn_mfma_f32_16x16x32_bf16(A[ct][0], Bf0, acc[ct], 0, 0,  \
                                                0);                            \
    _Pragma("unroll") for (int ct = 0; ct < 4; ++ct) acc[ct] =                 \
        __builtin_amdgcn_mfma_f32_16x16x32_bf16(A[ct][1], Bf1, acc[ct], 0, 0,  \
                                                0);                            \
    _Pragma("unroll") for (int ct = 0; ct < 4; ++ct) {                         \
      _Pragma("unroll") for (int r = 0; r < 4; ++r) {                          \
        const int c_ = ct * 16 + (l >> 4) * 4 + r;                             \
        const int zrow = c_ * 16 + (l & 15);                                   \
        zl[zrow * ZP + (w ^ (l >> 4))] = acc[ct][r];                           \
      }                                                                        \
    }                                                                          \
    BAR() /* A: x-reads + z-writes all done */                                 \
    if ((T) + 1 < NB) STAGE(STC)                                               \
    _Pragma("unroll") for (int t2 = 0; t2 < 4; ++t2) {                         \
      const int zrow = t2 * 256 + w * 32 + e;                                  \
      float4 v = *(const float4*)(zl + zrow * ZP + mq * 4);                    \
      if (g2 & 1) {                                                            \
        float t = v.x; v.x = v.y; v.y = t;                                     \
        t = v.z; v.z = v.w; v.w = t;                                           \
      }                                                                        \
      if (g2 & 2) {                                                            \
        float t = v.x; v.x = v.z; v.z = t;                                     \
        t = v.y; v.y = v.w; v.w = t;                                           \
      }                                                                        \
      *(float4*)(out + (size_t)((b0 + (T)*BT + (zrow & 15)) * Cc +             \
                                (zrow >> 4)) * Mm + m0 + mq * 4) = v;          \
    }                                                                          \
    if ((T) < NB - 1) BAR() /* B: x staged + z-reads done */                   \
  }

  ITER(0, st1, st0)
  ITER(1, st0, st1)
  ITER(2, st1, st0)
  ITER(3, st0, st1)
  ITER(4, st1, st0)
  ITER(5, st0, st1)
  ITER(6, st1, st0)
  ITER(7, st0, st1)

#undef ITER
#undef BAR
#undef STAGE
#undef ISSUE
}

extern "C" void kernel_launch(void* const* d_in, const int* in_sizes, int n_in,
                              void* d_out, int out_size, void* d_ws,
                              size_t ws_size, hipStream_t stream) {
  const float* x = (const float*)d_in[0];
  const float* mean = (const float*)d_in[1];
  const float* S = (const float*)d_in[2];
  float* out = (float*)d_out;
  const int nblocks = (Mm / MT) * (Bb / (BT * NB));  // 64 * 8 = 512
  hipLaunchKernelGGL(zca_v7, dim3(nblocks), dim3(512), LDSB, stream, x, mean,
                     S, out);
}